// Round 4
// baseline (1365.430 us; speedup 1.0000x reference)
//
#include <hip/hip_runtime.h>
#include <hip/hip_bf16.h>

#define HH 8
#define SS 128
#define CC 256
#define DD 32
#define NTOK 32768
#define NHB 2048
#define BNEPS 1e-5f

using bf16 = __hip_bfloat16;
typedef float f32x4 __attribute__((ext_vector_type(4)));
typedef __bf16 bf16x8 __attribute__((ext_vector_type(8)));

__device__ __forceinline__ bf16x8 ld8(const bf16* p) {
    return *reinterpret_cast<const bf16x8*>(p);
}
__device__ __forceinline__ f32x4 ldf4(const float* p) {
    return *reinterpret_cast<const f32x4*>(p);
}

// ---------------- fp32 -> bf16 weight conversion (all 6 weights, 1 launch) ----------------
__global__ void cvt6(const float* __restrict__ wq, const float* __restrict__ wk,
                     const float* __restrict__ wv, const float* __restrict__ wo,
                     const float* __restrict__ w0, const float* __restrict__ w1,
                     bf16* __restrict__ out) {
    int i = (blockIdx.x * 256 + threadIdx.x) * 4;  // 0..524284
    const float* src;
    int off;
    if (i < 65536) { src = wq; off = i; }
    else if (i < 131072) { src = wk; off = i - 65536; }
    else if (i < 196608) { src = wv; off = i - 131072; }
    else if (i < 262144) { src = wo; off = i - 196608; }
    else if (i < 393216) { src = w0; off = i - 262144; }
    else { src = w1; off = i - 393216; }
    f32x4 v = ldf4(src + off);
#pragma unroll
    for (int u = 0; u < 4; u++) out[i + u] = __float2bfloat16(v[u]);
}

// ---------------- vectorized BN stats ----------------
// CH: channels (pow2). RPP: rows covered per x-pass. grid.x*256 == (CH/VEC)*RPP.
template <typename T, int CH, int RPP>
__global__ __launch_bounds__(256) void stats_k(const T* __restrict__ X, int iters,
                                               float* __restrict__ sum,
                                               float* __restrict__ sumsq) {
    constexpr int VEC = (sizeof(T) == 2) ? 8 : 4;
    constexpr int COLV = CH / VEC;
    int gx = blockIdx.x * 256 + threadIdx.x;
    int cv = gx & (COLV - 1);
    int ro = gx / COLV;  // 0..RPP-1
    int c0 = cv * VEC;
    size_t row0 = (size_t)blockIdx.y * ((size_t)RPP * iters) + ro;
    float s[VEC], s2[VEC];
#pragma unroll
    for (int u = 0; u < VEC; u++) { s[u] = 0.f; s2[u] = 0.f; }
#pragma unroll 4
    for (int i = 0; i < iters; i++) {
        size_t row = row0 + (size_t)i * RPP;
        if constexpr (sizeof(T) == 2) {
            bf16x8 v = ld8((const bf16*)X + row * CH + c0);
#pragma unroll
            for (int u = 0; u < VEC; u++) {
                float f = (float)v[u];
                s[u] += f; s2[u] += f * f;
            }
        } else {
            f32x4 v = ldf4((const float*)X + row * CH + c0);
#pragma unroll
            for (int u = 0; u < VEC; u++) {
                float f = v[u];
                s[u] += f; s2[u] += f * f;
            }
        }
    }
#pragma unroll
    for (int u = 0; u < VEC; u++) {
        atomicAdd(&sum[c0 + u], s[u]);
        atomicAdd(&sumsq[c0 + u], s2[u]);
    }
}

// ---------------- stats -> per-channel scale/bias ----------------
__global__ void finalize_stats(const float* __restrict__ sum, const float* __restrict__ sumsq,
                               const float* __restrict__ gamma, const float* __restrict__ beta,
                               float* __restrict__ scale, float* __restrict__ bias,
                               float inv_n, int nch) {
    int c = blockIdx.x * 256 + threadIdx.x;
    if (c >= nch) return;
    float mean = sum[c] * inv_n;
    float var = sumsq[c] * inv_n - mean * mean;
    float rstd = rsqrtf(var + BNEPS);
    float sc = gamma[c] * rstd;
    scale[c] = sc;
    bias[c] = beta[c] - mean * sc;
}

// ---------------- vectorized BN apply (+ReLU) -> bf16 ----------------
template <bool RELU, int CH>
__global__ __launch_bounds__(256) void bn_apply_f32(const float* __restrict__ X,
                                                    bf16* __restrict__ out,
                                                    const float* __restrict__ scale,
                                                    const float* __restrict__ bias) {
    size_t base = ((size_t)blockIdx.x * 256 + threadIdx.x) * 8;
    int c0 = (int)(base & (size_t)(CH - 1));
    f32x4 x0 = ldf4(X + base), x1 = ldf4(X + base + 4);
    f32x4 s0 = ldf4(scale + c0), s1 = ldf4(scale + c0 + 4);
    f32x4 b0 = ldf4(bias + c0), b1 = ldf4(bias + c0 + 4);
    bf16x8 o;
#pragma unroll
    for (int u = 0; u < 4; u++) {
        float v = x0[u] * s0[u] + b0[u];
        if (RELU) v = fmaxf(v, 0.f);
        o[u] = (__bf16)__float2bfloat16(v);
    }
#pragma unroll
    for (int u = 0; u < 4; u++) {
        float v = x1[u] * s1[u] + b1[u];
        if (RELU) v = fmaxf(v, 0.f);
        o[u + 4] = (__bf16)__float2bfloat16(v);
    }
    *reinterpret_cast<bf16x8*>(out + base) = o;
}

template <bool RELU, int CH>
__global__ __launch_bounds__(256) void bn_apply_bf16(const bf16* __restrict__ X,
                                                     bf16* __restrict__ out,
                                                     const float* __restrict__ scale,
                                                     const float* __restrict__ bias) {
    size_t base = ((size_t)blockIdx.x * 256 + threadIdx.x) * 8;
    int c0 = (int)(base & (size_t)(CH - 1));
    bf16x8 xv = ld8(X + base);
    f32x4 s0 = ldf4(scale + c0), s1 = ldf4(scale + c0 + 4);
    f32x4 b0 = ldf4(bias + c0), b1 = ldf4(bias + c0 + 4);
    bf16x8 o;
#pragma unroll
    for (int u = 0; u < 4; u++) {
        float v = (float)xv[u] * s0[u] + b0[u];
        if (RELU) v = fmaxf(v, 0.f);
        o[u] = (__bf16)__float2bfloat16(v);
    }
#pragma unroll
    for (int u = 0; u < 4; u++) {
        float v = (float)xv[u + 4] * s1[u] + b1[u];
        if (RELU) v = fmaxf(v, 0.f);
        o[u + 4] = (__bf16)__float2bfloat16(v);
    }
    *reinterpret_cast<bf16x8*>(out + base) = o;
}

// ---------------- Fused QKV GEMM: [32768,256] x 3x[256,256]^T ----------------
// q,k stored [n,h,s,d]; v stored transposed [n,h,d,s]
__global__ __launch_bounds__(256) void gemm_qkv(
    const bf16* __restrict__ hbuf, const bf16* __restrict__ Wq,
    const bf16* __restrict__ Wk, const bf16* __restrict__ Wv,
    bf16* __restrict__ qb, bf16* __restrict__ kb, bf16* __restrict__ vtb) {
    int m0 = blockIdx.x * 64;
    int by = blockIdx.y;            // 0..11
    int mat = by >> 2;              // 0=q 1=k 2=v
    int n0 = (by & 3) * 64;
    const bf16* B = (mat == 0) ? Wq : ((mat == 1) ? Wk : Wv);
    int lane = threadIdx.x & 63, wave = threadIdx.x >> 6;
    int quad = lane >> 4, l16 = lane & 15;
    int wm = (wave >> 1) * 32, wn = (wave & 1) * 32;
    f32x4 zero = {0.f, 0.f, 0.f, 0.f};
    f32x4 acc[2][2];
#pragma unroll
    for (int i = 0; i < 2; i++)
#pragma unroll
        for (int j = 0; j < 2; j++) acc[i][j] = zero;
    const int K = CC;
#pragma unroll
    for (int kk = 0; kk < K; kk += 32) {
        int kb_ = kk + quad * 8;
        bf16x8 a0 = ld8(hbuf + (size_t)(m0 + wm + l16) * K + kb_);
        bf16x8 a1 = ld8(hbuf + (size_t)(m0 + wm + 16 + l16) * K + kb_);
        bf16x8 b0 = ld8(B + (size_t)(n0 + wn + l16) * K + kb_);
        bf16x8 b1 = ld8(B + (size_t)(n0 + wn + 16 + l16) * K + kb_);
        acc[0][0] = __builtin_amdgcn_mfma_f32_16x16x32_bf16(a0, b0, acc[0][0], 0, 0, 0);
        acc[0][1] = __builtin_amdgcn_mfma_f32_16x16x32_bf16(a0, b1, acc[0][1], 0, 0, 0);
        acc[1][0] = __builtin_amdgcn_mfma_f32_16x16x32_bf16(a1, b0, acc[1][0], 0, 0, 0);
        acc[1][1] = __builtin_amdgcn_mfma_f32_16x16x32_bf16(a1, b1, acc[1][1], 0, 0, 0);
    }
#pragma unroll
    for (int i = 0; i < 2; i++)
#pragma unroll
        for (int j = 0; j < 2; j++)
#pragma unroll
            for (int r = 0; r < 4; r++) {
                int row = m0 + wm + i * 16 + quad * 4 + r;  // token
                int col = n0 + wn + j * 16 + l16;           // channel
                float v = acc[i][j][r];
                int n = row >> 7, s = row & 127, hh = col >> 5, jd = col & 31;
                if (mat < 2) {
                    bf16* dst = (mat == 0) ? qb : kb;
                    dst[(((size_t)(n * HH + hh)) * SS + s) * DD + jd] = __float2bfloat16(v);
                } else {
                    vtb[(((size_t)(n * HH + hh)) * DD + jd) * SS + s] = __float2bfloat16(v);
                }
            }
}

// ---------------- energy = Q K^T per (n,h): [128,32]x[128,32]^T ----------------
__global__ __launch_bounds__(256) void gemm_energy(const bf16* __restrict__ qb,
                                                   const bf16* __restrict__ kbuf,
                                                   bf16* __restrict__ E) {
    int nh = blockIdx.z;
    const bf16* A = qb + (size_t)nh * SS * DD;
    const bf16* B = kbuf + (size_t)nh * SS * DD;
    int m0 = blockIdx.x * 64, n0 = blockIdx.y * 64;
    int lane = threadIdx.x & 63, wave = threadIdx.x >> 6;
    int quad = lane >> 4, l16 = lane & 15;
    int wm = (wave >> 1) * 32, wn = (wave & 1) * 32;
    f32x4 zero = {0.f, 0.f, 0.f, 0.f};
    f32x4 acc[2][2];
#pragma unroll
    for (int i = 0; i < 2; i++)
#pragma unroll
        for (int j = 0; j < 2; j++) acc[i][j] = zero;
    int kb_ = quad * 8;  // K = 32, single step
    bf16x8 a0 = ld8(A + (size_t)(m0 + wm + l16) * DD + kb_);
    bf16x8 a1 = ld8(A + (size_t)(m0 + wm + 16 + l16) * DD + kb_);
    bf16x8 b0 = ld8(B + (size_t)(n0 + wn + l16) * DD + kb_);
    bf16x8 b1 = ld8(B + (size_t)(n0 + wn + 16 + l16) * DD + kb_);
    acc[0][0] = __builtin_amdgcn_mfma_f32_16x16x32_bf16(a0, b0, acc[0][0], 0, 0, 0);
    acc[0][1] = __builtin_amdgcn_mfma_f32_16x16x32_bf16(a0, b1, acc[0][1], 0, 0, 0);
    acc[1][0] = __builtin_amdgcn_mfma_f32_16x16x32_bf16(a1, b0, acc[1][0], 0, 0, 0);
    acc[1][1] = __builtin_amdgcn_mfma_f32_16x16x32_bf16(a1, b1, acc[1][1], 0, 0, 0);
    bf16* Eb = E + (size_t)nh * SS * SS;
#pragma unroll
    for (int i = 0; i < 2; i++)
#pragma unroll
        for (int j = 0; j < 2; j++)
#pragma unroll
            for (int r = 0; r < 4; r++) {
                int row = m0 + wm + i * 16 + quad * 4 + r;
                int col = n0 + wn + j * 16 + l16;
                Eb[(size_t)row * SS + col] = __float2bfloat16(acc[i][j][r]);
            }
}

// ---------------- BN(energy) + softmax + P V^T per (n,h) ----------------
__global__ __launch_bounds__(256) void att_kernel(
    const bf16* __restrict__ E, const bf16* __restrict__ vt,
    const float* __restrict__ pe_scale, const float* __restrict__ pe_bias,
    bf16* __restrict__ o) {
    __shared__ bf16 P[SS][136];  // stride 272B: 16B-aligned rows, 2-way max bank aliasing
    int nh = blockIdx.x;
    const bf16* Eb = E + (size_t)nh * SS * SS;
    int tid = threadIdx.x;
    // phase 1: affine-BN + 1/sqrt(C) scale -> LDS logits (bf16)
#pragma unroll
    for (int t = 0; t < 8; t++) {
        int e8 = (t * 256 + tid) * 8;
        bf16x8 ev = ld8(Eb + e8);
        f32x4 s0 = ldf4(pe_scale + e8), s1 = ldf4(pe_scale + e8 + 4);
        f32x4 b0 = ldf4(pe_bias + e8), b1 = ldf4(pe_bias + e8 + 4);
        int qi = e8 >> 7, ki = e8 & 127;
        bf16x8 pv;
#pragma unroll
        for (int u = 0; u < 4; u++)
            pv[u] = (__bf16)__float2bfloat16(((float)ev[u] * s0[u] + b0[u]) * 0.0625f);
#pragma unroll
        for (int u = 0; u < 4; u++)
            pv[u + 4] = (__bf16)__float2bfloat16(((float)ev[u + 4] * s1[u] + b1[u]) * 0.0625f);
        *reinterpret_cast<bf16x8*>(&P[qi][ki]) = pv;
    }
    __syncthreads();
    // phase 2: softmax, one wave owns rows [wave*32, wave*32+32)
    int wave = tid >> 6, lane = tid & 63;
    for (int rr = 0; rr < 32; rr++) {
        int r = wave * 32 + rr;
        float x0 = (float)P[r][lane];
        float x1 = (float)P[r][lane + 64];
        float mx = fmaxf(x0, x1);
#pragma unroll
        for (int off = 32; off; off >>= 1) mx = fmaxf(mx, __shfl_xor(mx, off, 64));
        float e0 = __expf(x0 - mx), e1 = __expf(x1 - mx);
        float sm = e0 + e1;
#pragma unroll
        for (int off = 32; off; off >>= 1) sm += __shfl_xor(sm, off, 64);
        float inv = 1.0f / sm;
        P[r][lane] = __float2bfloat16(e0 * inv);
        P[r][lane + 64] = __float2bfloat16(e1 * inv);
    }
    __syncthreads();
    // phase 3: O = P @ V^T  (wave covers rows wave*32..+31, all 32 d-cols)
    int quad = lane >> 4, l16 = lane & 15;
    const bf16* V = vt + (size_t)nh * DD * SS;
    f32x4 zero = {0.f, 0.f, 0.f, 0.f};
    f32x4 acc[2][2];
#pragma unroll
    for (int i = 0; i < 2; i++)
#pragma unroll
        for (int j = 0; j < 2; j++) acc[i][j] = zero;
#pragma unroll
    for (int kk = 0; kk < SS; kk += 32) {
        int kb_ = kk + quad * 8;
        bf16x8 a0 = ld8(&P[wave * 32 + l16][kb_]);
        bf16x8 a1 = ld8(&P[wave * 32 + 16 + l16][kb_]);
        bf16x8 b0 = ld8(V + (size_t)(l16)*SS + kb_);
        bf16x8 b1 = ld8(V + (size_t)(16 + l16) * SS + kb_);
        acc[0][0] = __builtin_amdgcn_mfma_f32_16x16x32_bf16(a0, b0, acc[0][0], 0, 0, 0);
        acc[0][1] = __builtin_amdgcn_mfma_f32_16x16x32_bf16(a0, b1, acc[0][1], 0, 0, 0);
        acc[1][0] = __builtin_amdgcn_mfma_f32_16x16x32_bf16(a1, b0, acc[1][0], 0, 0, 0);
        acc[1][1] = __builtin_amdgcn_mfma_f32_16x16x32_bf16(a1, b1, acc[1][1], 0, 0, 0);
    }
    int nb = nh >> 3, hh = nh & 7;
#pragma unroll
    for (int i = 0; i < 2; i++)
#pragma unroll
        for (int j = 0; j < 2; j++)
#pragma unroll
            for (int r = 0; r < 4; r++) {
                int row_s = wave * 32 + i * 16 + quad * 4 + r;
                int jd = j * 16 + l16;
                int token = nb * SS + row_s;
                o[(size_t)token * CC + hh * DD + jd] = __float2bfloat16(acc[i][j][r]);
            }
}

// ---------------- Generic NT GEMM with epilogue modes ----------------
// MODE 0: out2 = A@B^T, store bf16
// MODE 1: x1 = A@B^T + bias + resf, store fp32
// MODE 2: out = A@B^T + resf, store fp32
template <int MODE>
__global__ __launch_bounds__(256) void gemm_nt(
    const bf16* __restrict__ A, const bf16* __restrict__ B, int N, int K,
    const float* __restrict__ bias, const float* __restrict__ resf,
    bf16* __restrict__ outb, float* __restrict__ outf) {
    int m0 = blockIdx.x * 64, n0 = blockIdx.y * 64;
    int lane = threadIdx.x & 63, wave = threadIdx.x >> 6;
    int quad = lane >> 4, l16 = lane & 15;
    int wm = (wave >> 1) * 32, wn = (wave & 1) * 32;
    f32x4 zero = {0.f, 0.f, 0.f, 0.f};
    f32x4 acc[2][2];
#pragma unroll
    for (int i = 0; i < 2; i++)
#pragma unroll
        for (int j = 0; j < 2; j++) acc[i][j] = zero;
    for (int kk = 0; kk < K; kk += 32) {
        int kb_ = kk + quad * 8;
        bf16x8 a0 = ld8(A + (size_t)(m0 + wm + l16) * K + kb_);
        bf16x8 a1 = ld8(A + (size_t)(m0 + wm + 16 + l16) * K + kb_);
        bf16x8 b0 = ld8(B + (size_t)(n0 + wn + l16) * K + kb_);
        bf16x8 b1 = ld8(B + (size_t)(n0 + wn + 16 + l16) * K + kb_);
        acc[0][0] = __builtin_amdgcn_mfma_f32_16x16x32_bf16(a0, b0, acc[0][0], 0, 0, 0);
        acc[0][1] = __builtin_amdgcn_mfma_f32_16x16x32_bf16(a0, b1, acc[0][1], 0, 0, 0);
        acc[1][0] = __builtin_amdgcn_mfma_f32_16x16x32_bf16(a1, b0, acc[1][0], 0, 0, 0);
        acc[1][1] = __builtin_amdgcn_mfma_f32_16x16x32_bf16(a1, b1, acc[1][1], 0, 0, 0);
    }
#pragma unroll
    for (int i = 0; i < 2; i++)
#pragma unroll
        for (int j = 0; j < 2; j++)
#pragma unroll
            for (int r = 0; r < 4; r++) {
                int row = m0 + wm + i * 16 + quad * 4 + r;
                int col = n0 + wn + j * 16 + l16;
                float v = acc[i][j][r];
                size_t idx = (size_t)row * N + col;
                if (MODE == 0) {
                    outb[idx] = __float2bfloat16(v);
                } else if (MODE == 1) {
                    outf[idx] = v + bias[col] + resf[idx];
                } else {
                    outf[idx] = v + resf[idx];
                }
            }
}

// ---------------- workspace layout (bytes) ----------------
#define WB_OFF 0u
#define HB_OFF 1048576u
#define Q_OFF 17825792u
#define K_OFF 34603008u
#define VT_OFF 51380224u
#define E_OFF 68157440u
#define O_OFF 1048576u      /* reuse hbuf */
#define X1_OFF 17825792u    /* fp32, over q+k */
#define OUT1_OFF 51380224u  /* over vt */
#define OUT2_OFF 68157440u  /* over E 1st half */
#define OUT4_OFF 101711872u /* over E 2nd half */
#define STATS_OFF 135266304u
#define STATS_FLOATS 34816u
/* transient scale/bias homes (dead windows):
   bn1 s/b -> E_OFF   (E not written until energy gemm)
   pe  s/b -> Q_OFF   (q,k dead after energy; x1 written later)
   bn0 s/b -> HB_OFF  (obuf dead after Wo gemm)
   f1  s/b -> HB_OFF + 8192 */

extern "C" void kernel_launch(void* const* d_in, const int* in_sizes, int n_in,
                              void* d_out, int out_size, void* d_ws, size_t ws_size,
                              hipStream_t stream) {
    const float* x = (const float*)d_in[0];
    const float* g_n = (const float*)d_in[1];
    const float* b_n = (const float*)d_in[2];
    const float* Wq = (const float*)d_in[3];
    const float* Wk = (const float*)d_in[4];
    const float* Wv = (const float*)d_in[5];
    const float* Wo = (const float*)d_in[6];
    const float* bo = (const float*)d_in[7];
    const float* g_pe = (const float*)d_in[8];
    const float* b_pe = (const float*)d_in[9];
    const float* g0 = (const float*)d_in[10];
    const float* b0 = (const float*)d_in[11];
    const float* W0 = (const float*)d_in[12];
    const float* g1 = (const float*)d_in[13];
    const float* b1 = (const float*)d_in[14];
    const float* W1 = (const float*)d_in[15];

    char* ws = (char*)d_ws;
    bf16* WB = (bf16*)(ws + WB_OFF);
    bf16* WQB = WB;
    bf16* WKB = WB + 65536;
    bf16* WVB = WB + 131072;
    bf16* WOB = WB + 196608;
    bf16* W0B = WB + 262144;
    bf16* W1B = WB + 393216;
    bf16* hbuf = (bf16*)(ws + HB_OFF);
    bf16* qb = (bf16*)(ws + Q_OFF);
    bf16* kb = (bf16*)(ws + K_OFF);
    bf16* vtb = (bf16*)(ws + VT_OFF);
    bf16* Ebuf = (bf16*)(ws + E_OFF);
    bf16* obuf = (bf16*)(ws + O_OFF);
    float* x1 = (float*)(ws + X1_OFF);
    bf16* out1 = (bf16*)(ws + OUT1_OFF);
    bf16* out2 = (bf16*)(ws + OUT2_OFF);
    bf16* out4 = (bf16*)(ws + OUT4_OFF);
    float* stats = (float*)(ws + STATS_OFF);
    float* bn1_sum = stats;
    float* bn1_sq = stats + 256;
    float* pe_sum = stats + 512;
    float* pe_sq = stats + 512 + 16384;
    float* bn0_sum = stats + 33280;
    float* bn0_sq = stats + 33536;
    float* f1_sum = stats + 33792;
    float* f1_sq = stats + 34304;
    // transient scale/bias
    float* bn1_scale = (float*)(ws + E_OFF);
    float* bn1_bias = bn1_scale + 256;
    float* pe_scale = (float*)(ws + Q_OFF);
    float* pe_bias = pe_scale + 16384;
    float* bn0_scale = (float*)(ws + HB_OFF);
    float* bn0_bias = bn0_scale + 256;
    float* f1_scale = (float*)(ws + HB_OFF + 8192);
    float* f1_bias = f1_scale + 512;
    float* outp = (float*)d_out;

    hipMemsetAsync(ws + STATS_OFF, 0, STATS_FLOATS * 4, stream);

    // weights fp32 -> bf16
    cvt6<<<512, 256, 0, stream>>>(Wq, Wk, Wv, Wo, W0, W1, WB);
    // --- BN(x) ---
    stats_k<float, 256, 4><<<dim3(1, 512), 256, 0, stream>>>(x, 16, bn1_sum, bn1_sq);
    finalize_stats<<<1, 256, 0, stream>>>(bn1_sum, bn1_sq, g_n, b_n, bn1_scale, bn1_bias,
                                          1.0f / 32768.0f, 256);
    bn_apply_f32<false, 256><<<4096, 256, 0, stream>>>(x, hbuf, bn1_scale, bn1_bias);
    // QKV
    gemm_qkv<<<dim3(512, 12), 256, 0, stream>>>(hbuf, WQB, WKB, WVB, qb, kb, vtb);
    // energy
    gemm_energy<<<dim3(2, 2, NHB), 256, 0, stream>>>(qb, kb, Ebuf);
    // --- BN(energy) ---
    stats_k<bf16, 16384, 1><<<dim3(8, 64), 256, 0, stream>>>(Ebuf, 32, pe_sum, pe_sq);
    finalize_stats<<<64, 256, 0, stream>>>(pe_sum, pe_sq, g_pe, b_pe, pe_scale, pe_bias,
                                           1.0f / 2048.0f, 16384);
    // BN + softmax + PV
    att_kernel<<<NHB, 256, 0, stream>>>(Ebuf, vtb, pe_scale, pe_bias, obuf);
    // x1 = o @ Wo^T + bo + x   (fp32)
    gemm_nt<1><<<dim3(512, 4), 256, 0, stream>>>(obuf, WOB, CC, CC, bo, x, nullptr, x1);
    // --- BN(x1) ---
    stats_k<float, 256, 4><<<dim3(1, 512), 256, 0, stream>>>(x1, 16, bn0_sum, bn0_sq);
    finalize_stats<<<1, 256, 0, stream>>>(bn0_sum, bn0_sq, g0, b0, bn0_scale, bn0_bias,
                                          1.0f / 32768.0f, 256);
    bn_apply_f32<true, 256><<<4096, 256, 0, stream>>>(x1, out1, bn0_scale, bn0_bias);
    gemm_nt<0><<<dim3(512, 8), 256, 0, stream>>>(out1, W0B, 2 * CC, CC, nullptr, nullptr,
                                                 out2, nullptr);
    // --- BN(out2) ---
    stats_k<bf16, 512, 4><<<dim3(1, 512), 256, 0, stream>>>(out2, 16, f1_sum, f1_sq);
    finalize_stats<<<2, 256, 0, stream>>>(f1_sum, f1_sq, g1, b1, f1_scale, f1_bias,
                                          1.0f / 32768.0f, 512);
    bn_apply_bf16<true, 512><<<8192, 256, 0, stream>>>(out2, out4, f1_scale, f1_bias);
    gemm_nt<2><<<dim3(512, 4), 256, 0, stream>>>(out4, W1B, CC, 2 * CC, nullptr, x1,
                                                 nullptr, outp);
    (void)in_sizes; (void)n_in; (void)out_size; (void)ws_size;
}

// Round 7
// 623.078 us; speedup vs baseline: 2.1914x; 2.1914x over previous
//
#include <hip/hip_runtime.h>
#include <hip/hip_bf16.h>

#define HH 8
#define SS 128
#define CC 256
#define DD 32
#define NTOK 32768
#define NHB 2048
#define BNEPS 1e-5f

using bf16 = __hip_bfloat16;
typedef float f32x4 __attribute__((ext_vector_type(4)));
typedef __bf16 bf16x8 __attribute__((ext_vector_type(8)));

__device__ __forceinline__ bf16x8 ld8(const bf16* p) {
    return *reinterpret_cast<const bf16x8*>(p);
}
__device__ __forceinline__ f32x4 ldf4(const float* p) {
    return *reinterpret_cast<const f32x4*>(p);
}

// ---------------- fp32 -> bf16 weight conversion (all 6 weights, 1 launch) ----------------
__global__ void cvt6(const float* __restrict__ wq, const float* __restrict__ wk,
                     const float* __restrict__ wv, const float* __restrict__ wo,
                     const float* __restrict__ w0, const float* __restrict__ w1,
                     bf16* __restrict__ out) {
    int i = (blockIdx.x * 256 + threadIdx.x) * 4;  // 0..524284
    const float* src;
    int off;
    if (i < 65536) { src = wq; off = i; }
    else if (i < 131072) { src = wk; off = i - 65536; }
    else if (i < 196608) { src = wv; off = i - 131072; }
    else if (i < 262144) { src = wo; off = i - 196608; }
    else if (i < 393216) { src = w0; off = i - 262144; }
    else { src = w1; off = i - 393216; }
    f32x4 v = ldf4(src + off);
#pragma unroll
    for (int u = 0; u < 4; u++) out[i + u] = __float2bfloat16(v[u]);
}

// ---------------- stats stage A (small CH): block-local LDS reduce, NO atomics ----------------
// partial layout: part[p][0..CH-1]=sum, part[p][CH..2CH-1]=sumsq  (P=grid.x rows)
template <typename T, int CH, int P>
__global__ __launch_bounds__(256) void statsA_small(const T* __restrict__ X,
                                                    float* __restrict__ part) {
    constexpr int VEC = (sizeof(T) == 2) ? 8 : 4;
    constexpr int COLV = CH / VEC;
    constexpr int SLOTS = 256 / COLV;
    constexpr int RB = NTOK / P;
    constexpr int ITER = RB / SLOTS;
    int tid = threadIdx.x;
    int cv = tid & (COLV - 1), slot = tid / COLV;
    int c0 = cv * VEC;
    size_t row0 = (size_t)blockIdx.x * RB + slot;
    float s[VEC], s2[VEC];
#pragma unroll
    for (int u = 0; u < VEC; u++) { s[u] = 0.f; s2[u] = 0.f; }
    for (int i = 0; i < ITER; i++) {
        size_t row = row0 + (size_t)i * SLOTS;
        if constexpr (sizeof(T) == 2) {
            bf16x8 v = ld8((const bf16*)X + row * CH + c0);
#pragma unroll
            for (int u = 0; u < VEC; u++) {
                float f = (float)v[u];
                s[u] += f; s2[u] += f * f;
            }
        } else {
            f32x4 v = ldf4((const float*)X + row * CH + c0);
#pragma unroll
            for (int u = 0; u < VEC; u++) {
                float f = v[u];
                s[u] += f; s2[u] += f * f;
            }
        }
    }
    __shared__ float red[256][2 * VEC];
#pragma unroll
    for (int u = 0; u < VEC; u++) {
        red[tid][u] = s[u];
        red[tid][VEC + u] = s2[u];
    }
    __syncthreads();
    if (tid < COLV) {
#pragma unroll
        for (int sl = 1; sl < SLOTS; sl++)
#pragma unroll
            for (int u = 0; u < VEC; u++) {
                s[u] += red[tid + sl * COLV][u];
                s2[u] += red[tid + sl * COLV][VEC + u];
            }
        float* dst = part + (size_t)blockIdx.x * (2 * CH);
#pragma unroll
        for (int u = 0; u < VEC; u++) {
            dst[c0 + u] = s[u];
            dst[CH + c0 + u] = s2[u];
        }
    }
}

// ---------------- stats stage A (wide CH, bf16): disjoint channels, NO atomics ----------------
template <int CH, int P, int ROWS>
__global__ __launch_bounds__(256) void statsA_wide(const bf16* __restrict__ X,
                                                   float* __restrict__ part) {
    constexpr int RB = ROWS / P;
    int c0 = (blockIdx.x * 256 + threadIdx.x) * 8;
    size_t row0 = (size_t)blockIdx.y * RB;
    float s[8], s2[8];
#pragma unroll
    for (int u = 0; u < 8; u++) { s[u] = 0.f; s2[u] = 0.f; }
    for (int i = 0; i < RB; i++) {
        bf16x8 v = ld8(X + (row0 + i) * CH + c0);
#pragma unroll
        for (int u = 0; u < 8; u++) {
            float f = (float)v[u];
            s[u] += f; s2[u] += f * f;
        }
    }
    float* dst = part + (size_t)blockIdx.y * (2 * CH);
#pragma unroll
    for (int u = 0; u < 8; u++) {
        dst[c0 + u] = s[u];
        dst[CH + c0 + u] = s2[u];
    }
}

// ---------------- stage B: reduce partials + finalize -> scale/bias ----------------
__global__ void statsB(const float* __restrict__ part, int P, int nch, float inv_n,
                       const float* __restrict__ gamma, const float* __restrict__ beta,
                       float* __restrict__ scale, float* __restrict__ bias) {
    int c = blockIdx.x * 256 + threadIdx.x;
    if (c >= nch) return;
    float s = 0.f, s2 = 0.f;
    for (int p = 0; p < P; p++) {
        s += part[(size_t)p * 2 * nch + c];
        s2 += part[(size_t)p * 2 * nch + nch + c];
    }
    float mean = s * inv_n;
    float var = s2 * inv_n - mean * mean;
    float rstd = rsqrtf(var + BNEPS);
    float sc = gamma[c] * rstd;
    scale[c] = sc;
    bias[c] = beta[c] - mean * sc;
}

// ---------------- vectorized BN apply (+ReLU) -> bf16 ----------------
template <bool RELU, int CH>
__global__ __launch_bounds__(256) void bn_apply_f32(const float* __restrict__ X,
                                                    bf16* __restrict__ out,
                                                    const float* __restrict__ scale,
                                                    const float* __restrict__ bias) {
    size_t base = ((size_t)blockIdx.x * 256 + threadIdx.x) * 8;
    int c0 = (int)(base & (size_t)(CH - 1));
    f32x4 x0 = ldf4(X + base), x1 = ldf4(X + base + 4);
    f32x4 s0 = ldf4(scale + c0), s1 = ldf4(scale + c0 + 4);
    f32x4 b0 = ldf4(bias + c0), b1 = ldf4(bias + c0 + 4);
    bf16x8 o;
#pragma unroll
    for (int u = 0; u < 4; u++) {
        float v = x0[u] * s0[u] + b0[u];
        if (RELU) v = fmaxf(v, 0.f);
        o[u] = (__bf16)__float2bfloat16(v);
    }
#pragma unroll
    for (int u = 0; u < 4; u++) {
        float v = x1[u] * s1[u] + b1[u];
        if (RELU) v = fmaxf(v, 0.f);
        o[u + 4] = (__bf16)__float2bfloat16(v);
    }
    *reinterpret_cast<bf16x8*>(out + base) = o;
}

template <bool RELU, int CH>
__global__ __launch_bounds__(256) void bn_apply_bf16(const bf16* __restrict__ X,
                                                     bf16* __restrict__ out,
                                                     const float* __restrict__ scale,
                                                     const float* __restrict__ bias) {
    size_t base = ((size_t)blockIdx.x * 256 + threadIdx.x) * 8;
    int c0 = (int)(base & (size_t)(CH - 1));
    bf16x8 xv = ld8(X + base);
    f32x4 s0 = ldf4(scale + c0), s1 = ldf4(scale + c0 + 4);
    f32x4 b0 = ldf4(bias + c0), b1 = ldf4(bias + c0 + 4);
    bf16x8 o;
#pragma unroll
    for (int u = 0; u < 4; u++) {
        float v = (float)xv[u] * s0[u] + b0[u];
        if (RELU) v = fmaxf(v, 0.f);
        o[u] = (__bf16)__float2bfloat16(v);
    }
#pragma unroll
    for (int u = 0; u < 4; u++) {
        float v = (float)xv[u + 4] * s1[u] + b1[u];
        if (RELU) v = fmaxf(v, 0.f);
        o[u + 4] = (__bf16)__float2bfloat16(v);
    }
    *reinterpret_cast<bf16x8*>(out + base) = o;
}

// ---------------- Fused QKV GEMM: [32768,256] x 3x[256,256]^T ----------------
// q,k stored [n,h,s,d]; v stored transposed [n,h,d,s]
__global__ __launch_bounds__(256) void gemm_qkv(
    const bf16* __restrict__ hbuf, const bf16* __restrict__ Wq,
    const bf16* __restrict__ Wk, const bf16* __restrict__ Wv,
    bf16* __restrict__ qb, bf16* __restrict__ kb, bf16* __restrict__ vtb) {
    int m0 = blockIdx.x * 64;
    int by = blockIdx.y;            // 0..11
    int mat = by >> 2;              // 0=q 1=k 2=v
    int n0 = (by & 3) * 64;
    const bf16* B = (mat == 0) ? Wq : ((mat == 1) ? Wk : Wv);
    int lane = threadIdx.x & 63, wave = threadIdx.x >> 6;
    int quad = lane >> 4, l16 = lane & 15;
    int wm = (wave >> 1) * 32, wn = (wave & 1) * 32;
    f32x4 zero = {0.f, 0.f, 0.f, 0.f};
    f32x4 acc[2][2];
#pragma unroll
    for (int i = 0; i < 2; i++)
#pragma unroll
        for (int j = 0; j < 2; j++) acc[i][j] = zero;
    const int K = CC;
#pragma unroll
    for (int kk = 0; kk < K; kk += 32) {
        int kb_ = kk + quad * 8;
        bf16x8 a0 = ld8(hbuf + (size_t)(m0 + wm + l16) * K + kb_);
        bf16x8 a1 = ld8(hbuf + (size_t)(m0 + wm + 16 + l16) * K + kb_);
        bf16x8 b0 = ld8(B + (size_t)(n0 + wn + l16) * K + kb_);
        bf16x8 b1 = ld8(B + (size_t)(n0 + wn + 16 + l16) * K + kb_);
        acc[0][0] = __builtin_amdgcn_mfma_f32_16x16x32_bf16(a0, b0, acc[0][0], 0, 0, 0);
        acc[0][1] = __builtin_amdgcn_mfma_f32_16x16x32_bf16(a0, b1, acc[0][1], 0, 0, 0);
        acc[1][0] = __builtin_amdgcn_mfma_f32_16x16x32_bf16(a1, b0, acc[1][0], 0, 0, 0);
        acc[1][1] = __builtin_amdgcn_mfma_f32_16x16x32_bf16(a1, b1, acc[1][1], 0, 0, 0);
    }
#pragma unroll
    for (int i = 0; i < 2; i++)
#pragma unroll
        for (int j = 0; j < 2; j++)
#pragma unroll
            for (int r = 0; r < 4; r++) {
                int row = m0 + wm + i * 16 + quad * 4 + r;  // token
                int col = n0 + wn + j * 16 + l16;           // channel
                float v = acc[i][j][r];
                int n = row >> 7, s = row & 127, hh = col >> 5, jd = col & 31;
                if (mat < 2) {
                    bf16* dst = (mat == 0) ? qb : kb;
                    dst[(((size_t)(n * HH + hh)) * SS + s) * DD + jd] = __float2bfloat16(v);
                } else {
                    vtb[(((size_t)(n * HH + hh)) * DD + jd) * SS + s] = __float2bfloat16(v);
                }
            }
}

// ---------------- energy = Q K^T per (n,h): [128,32]x[128,32]^T ----------------
__global__ __launch_bounds__(256) void gemm_energy(const bf16* __restrict__ qb,
                                                   const bf16* __restrict__ kbuf,
                                                   bf16* __restrict__ E) {
    int nh = blockIdx.z;
    const bf16* A = qb + (size_t)nh * SS * DD;
    const bf16* B = kbuf + (size_t)nh * SS * DD;
    int m0 = blockIdx.x * 64, n0 = blockIdx.y * 64;
    int lane = threadIdx.x & 63, wave = threadIdx.x >> 6;
    int quad = lane >> 4, l16 = lane & 15;
    int wm = (wave >> 1) * 32, wn = (wave & 1) * 32;
    f32x4 zero = {0.f, 0.f, 0.f, 0.f};
    f32x4 acc[2][2];
#pragma unroll
    for (int i = 0; i < 2; i++)
#pragma unroll
        for (int j = 0; j < 2; j++) acc[i][j] = zero;
    int kb_ = quad * 8;  // K = 32, single step
    bf16x8 a0 = ld8(A + (size_t)(m0 + wm + l16) * DD + kb_);
    bf16x8 a1 = ld8(A + (size_t)(m0 + wm + 16 + l16) * DD + kb_);
    bf16x8 b0 = ld8(B + (size_t)(n0 + wn + l16) * DD + kb_);
    bf16x8 b1 = ld8(B + (size_t)(n0 + wn + 16 + l16) * DD + kb_);
    acc[0][0] = __builtin_amdgcn_mfma_f32_16x16x32_bf16(a0, b0, acc[0][0], 0, 0, 0);
    acc[0][1] = __builtin_amdgcn_mfma_f32_16x16x32_bf16(a0, b1, acc[0][1], 0, 0, 0);
    acc[1][0] = __builtin_amdgcn_mfma_f32_16x16x32_bf16(a1, b0, acc[1][0], 0, 0, 0);
    acc[1][1] = __builtin_amdgcn_mfma_f32_16x16x32_bf16(a1, b1, acc[1][1], 0, 0, 0);
    bf16* Eb = E + (size_t)nh * SS * SS;
#pragma unroll
    for (int i = 0; i < 2; i++)
#pragma unroll
        for (int j = 0; j < 2; j++)
#pragma unroll
            for (int r = 0; r < 4; r++) {
                int row = m0 + wm + i * 16 + quad * 4 + r;
                int col = n0 + wn + j * 16 + l16;
                Eb[(size_t)row * SS + col] = __float2bfloat16(acc[i][j][r]);
            }
}

// ---------------- BN(energy) + softmax + P V^T per (n,h) ----------------
__global__ __launch_bounds__(256) void att_kernel(
    const bf16* __restrict__ E, const bf16* __restrict__ vt,
    const float* __restrict__ pe_scale, const float* __restrict__ pe_bias,
    bf16* __restrict__ o) {
    __shared__ bf16 P[SS][136];  // stride 272B: 16B-aligned rows, 2-way max bank aliasing
    int nh = blockIdx.x;
    const bf16* Eb = E + (size_t)nh * SS * SS;
    int tid = threadIdx.x;
    // phase 1: affine-BN + 1/sqrt(C) scale -> LDS logits (bf16)
#pragma unroll
    for (int t = 0; t < 8; t++) {
        int e8 = (t * 256 + tid) * 8;
        bf16x8 ev = ld8(Eb + e8);
        f32x4 s0 = ldf4(pe_scale + e8), s1 = ldf4(pe_scale + e8 + 4);
        f32x4 b0 = ldf4(pe_bias + e8), b1 = ldf4(pe_bias + e8 + 4);
        int qi = e8 >> 7, ki = e8 & 127;
        bf16x8 pv;
#pragma unroll
        for (int u = 0; u < 4; u++)
            pv[u] = (__bf16)__float2bfloat16(((float)ev[u] * s0[u] + b0[u]) * 0.0625f);
#pragma unroll
        for (int u = 0; u < 4; u++)
            pv[u + 4] = (__bf16)__float2bfloat16(((float)ev[u + 4] * s1[u] + b1[u]) * 0.0625f);
        *reinterpret_cast<bf16x8*>(&P[qi][ki]) = pv;
    }
    __syncthreads();
    // phase 2: softmax, one wave owns rows [wave*32, wave*32+32)
    int wave = tid >> 6, lane = tid & 63;
    for (int rr = 0; rr < 32; rr++) {
        int r = wave * 32 + rr;
        float x0 = (float)P[r][lane];
        float x1 = (float)P[r][lane + 64];
        float mx = fmaxf(x0, x1);
#pragma unroll
        for (int off = 32; off; off >>= 1) mx = fmaxf(mx, __shfl_xor(mx, off, 64));
        float e0 = __expf(x0 - mx), e1 = __expf(x1 - mx);
        float sm = e0 + e1;
#pragma unroll
        for (int off = 32; off; off >>= 1) sm += __shfl_xor(sm, off, 64);
        float inv = 1.0f / sm;
        P[r][lane] = __float2bfloat16(e0 * inv);
        P[r][lane + 64] = __float2bfloat16(e1 * inv);
    }
    __syncthreads();
    // phase 3: O = P @ V^T  (wave covers rows wave*32..+31, all 32 d-cols)
    int quad = lane >> 4, l16 = lane & 15;
    const bf16* V = vt + (size_t)nh * DD * SS;
    f32x4 zero = {0.f, 0.f, 0.f, 0.f};
    f32x4 acc[2][2];
#pragma unroll
    for (int i = 0; i < 2; i++)
#pragma unroll
        for (int j = 0; j < 2; j++) acc[i][j] = zero;
#pragma unroll
    for (int kk = 0; kk < SS; kk += 32) {
        int kb_ = kk + quad * 8;
        bf16x8 a0 = ld8(&P[wave * 32 + l16][kb_]);
        bf16x8 a1 = ld8(&P[wave * 32 + 16 + l16][kb_]);
        bf16x8 b0 = ld8(V + (size_t)(l16)*SS + kb_);
        bf16x8 b1 = ld8(V + (size_t)(16 + l16) * SS + kb_);
        acc[0][0] = __builtin_amdgcn_mfma_f32_16x16x32_bf16(a0, b0, acc[0][0], 0, 0, 0);
        acc[0][1] = __builtin_amdgcn_mfma_f32_16x16x32_bf16(a0, b1, acc[0][1], 0, 0, 0);
        acc[1][0] = __builtin_amdgcn_mfma_f32_16x16x32_bf16(a1, b0, acc[1][0], 0, 0, 0);
        acc[1][1] = __builtin_amdgcn_mfma_f32_16x16x32_bf16(a1, b1, acc[1][1], 0, 0, 0);
    }
    int nb = nh >> 3, hh = nh & 7;
#pragma unroll
    for (int i = 0; i < 2; i++)
#pragma unroll
        for (int j = 0; j < 2; j++)
#pragma unroll
            for (int r = 0; r < 4; r++) {
                int row_s = wave * 32 + i * 16 + quad * 4 + r;
                int jd = j * 16 + l16;
                int token = nb * SS + row_s;
                o[(size_t)token * CC + hh * DD + jd] = __float2bfloat16(acc[i][j][r]);
            }
}

// ---------------- Generic NT GEMM with epilogue modes ----------------
// MODE 0: out2 = A@B^T, store bf16
// MODE 1: x1 = A@B^T + bias + resf, store fp32
// MODE 2: out = A@B^T + resf, store fp32
template <int MODE>
__global__ __launch_bounds__(256) void gemm_nt(
    const bf16* __restrict__ A, const bf16* __restrict__ B, int N, int K,
    const float* __restrict__ bias, const float* __restrict__ resf,
    bf16* __restrict__ outb, float* __restrict__ outf) {
    int m0 = blockIdx.x * 64, n0 = blockIdx.y * 64;
    int lane = threadIdx.x & 63, wave = threadIdx.x >> 6;
    int quad = lane >> 4, l16 = lane & 15;
    int wm = (wave >> 1) * 32, wn = (wave & 1) * 32;
    f32x4 zero = {0.f, 0.f, 0.f, 0.f};
    f32x4 acc[2][2];
#pragma unroll
    for (int i = 0; i < 2; i++)
#pragma unroll
        for (int j = 0; j < 2; j++) acc[i][j] = zero;
    for (int kk = 0; kk < K; kk += 32) {
        int kb_ = kk + quad * 8;
        bf16x8 a0 = ld8(A + (size_t)(m0 + wm + l16) * K + kb_);
        bf16x8 a1 = ld8(A + (size_t)(m0 + wm + 16 + l16) * K + kb_);
        bf16x8 b0 = ld8(B + (size_t)(n0 + wn + l16) * K + kb_);
        bf16x8 b1 = ld8(B + (size_t)(n0 + wn + 16 + l16) * K + kb_);
        acc[0][0] = __builtin_amdgcn_mfma_f32_16x16x32_bf16(a0, b0, acc[0][0], 0, 0, 0);
        acc[0][1] = __builtin_amdgcn_mfma_f32_16x16x32_bf16(a0, b1, acc[0][1], 0, 0, 0);
        acc[1][0] = __builtin_amdgcn_mfma_f32_16x16x32_bf16(a1, b0, acc[1][0], 0, 0, 0);
        acc[1][1] = __builtin_amdgcn_mfma_f32_16x16x32_bf16(a1, b1, acc[1][1], 0, 0, 0);
    }
#pragma unroll
    for (int i = 0; i < 2; i++)
#pragma unroll
        for (int j = 0; j < 2; j++)
#pragma unroll
            for (int r = 0; r < 4; r++) {
                int row = m0 + wm + i * 16 + quad * 4 + r;
                int col = n0 + wn + j * 16 + l16;
                float v = acc[i][j][r];
                size_t idx = (size_t)row * N + col;
                if (MODE == 0) {
                    outb[idx] = __float2bfloat16(v);
                } else if (MODE == 1) {
                    outf[idx] = v + bias[col] + resf[idx];
                } else {
                    outf[idx] = v + resf[idx];
                }
            }
}

// ---------------- workspace layout (bytes) ----------------
#define WB_OFF 0u
#define HB_OFF 1048576u
#define Q_OFF 17825792u
#define K_OFF 34603008u
#define VT_OFF 51380224u
#define E_OFF 68157440u
#define O_OFF 1048576u      /* reuse hbuf */
#define X1_OFF 17825792u    /* fp32, over q+k */
#define OUT1_OFF 51380224u  /* over vt */
#define OUT2_OFF 68157440u  /* over E 1st half */
#define OUT4_OFF 101711872u /* over E 2nd half */
/* transient scale/bias + partial homes (dead windows):
   bn1 s/b  -> E_OFF (2 KB);      x  partial -> E_OFF+64K (256 KB)   [E dead until energy]
   pe  s/b  -> Q_OFF (128 KB);    pe partial -> Q_OFF+128K (4 MB)    [q dead after energy]
   bn0 s/b  -> HB_OFF (2 KB);     x1 partial -> HB_OFF+16K (256 KB)  [obuf dead after Wo gemm]
   f1  s/b  -> HB_OFF+4K (4 KB);  f1 partial -> HB_OFF+16K (512 KB) */

extern "C" void kernel_launch(void* const* d_in, const int* in_sizes, int n_in,
                              void* d_out, int out_size, void* d_ws, size_t ws_size,
                              hipStream_t stream) {
    const float* x = (const float*)d_in[0];
    const float* g_n = (const float*)d_in[1];
    const float* b_n = (const float*)d_in[2];
    const float* Wq = (const float*)d_in[3];
    const float* Wk = (const float*)d_in[4];
    const float* Wv = (const float*)d_in[5];
    const float* Wo = (const float*)d_in[6];
    const float* bo = (const float*)d_in[7];
    const float* g_pe = (const float*)d_in[8];
    const float* b_pe = (const float*)d_in[9];
    const float* g0 = (const float*)d_in[10];
    const float* b0 = (const float*)d_in[11];
    const float* W0 = (const float*)d_in[12];
    const float* g1 = (const float*)d_in[13];
    const float* b1 = (const float*)d_in[14];
    const float* W1 = (const float*)d_in[15];

    char* ws = (char*)d_ws;
    bf16* WB = (bf16*)(ws + WB_OFF);
    bf16* WQB = WB;
    bf16* WKB = WB + 65536;
    bf16* WVB = WB + 131072;
    bf16* WOB = WB + 196608;
    bf16* W0B = WB + 262144;
    bf16* W1B = WB + 393216;
    bf16* hbuf = (bf16*)(ws + HB_OFF);
    bf16* qb = (bf16*)(ws + Q_OFF);
    bf16* kb = (bf16*)(ws + K_OFF);
    bf16* vtb = (bf16*)(ws + VT_OFF);
    bf16* Ebuf = (bf16*)(ws + E_OFF);
    bf16* obuf = (bf16*)(ws + O_OFF);
    float* x1 = (float*)(ws + X1_OFF);
    bf16* out1 = (bf16*)(ws + OUT1_OFF);
    bf16* out2 = (bf16*)(ws + OUT2_OFF);
    bf16* out4 = (bf16*)(ws + OUT4_OFF);
    // scale/bias + partials in dead windows
    float* bn1_scale = (float*)(ws + E_OFF);
    float* bn1_bias = bn1_scale + 256;
    float* xpart = (float*)(ws + E_OFF + 65536);
    float* pe_scale = (float*)(ws + Q_OFF);
    float* pe_bias = pe_scale + 16384;
    float* pepart = (float*)(ws + Q_OFF + 131072);
    float* bn0_scale = (float*)(ws + HB_OFF);
    float* bn0_bias = bn0_scale + 256;
    float* f1_scale = (float*)(ws + HB_OFF + 4096);
    float* f1_bias = f1_scale + 512;
    float* x1part = (float*)(ws + HB_OFF + 16384);
    float* f1part = (float*)(ws + HB_OFF + 16384);
    float* outp = (float*)d_out;

    // weights fp32 -> bf16
    cvt6<<<512, 256, 0, stream>>>(Wq, Wk, Wv, Wo, W0, W1, WB);
    // --- BN(x) ---
    statsA_small<float, 256, 128><<<128, 256, 0, stream>>>(x, xpart);
    statsB<<<1, 256, 0, stream>>>(xpart, 128, 256, 1.0f / 32768.0f, g_n, b_n,
                                  bn1_scale, bn1_bias);
    bn_apply_f32<false, 256><<<4096, 256, 0, stream>>>(x, hbuf, bn1_scale, bn1_bias);
    // QKV
    gemm_qkv<<<dim3(512, 12), 256, 0, stream>>>(hbuf, WQB, WKB, WVB, qb, kb, vtb);
    // energy
    gemm_energy<<<dim3(2, 2, NHB), 256, 0, stream>>>(qb, kb, Ebuf);
    // --- BN(energy) ---
    statsA_wide<16384, 32, 2048><<<dim3(8, 32), 256, 0, stream>>>(Ebuf, pepart);
    statsB<<<64, 256, 0, stream>>>(pepart, 32, 16384, 1.0f / 2048.0f, g_pe, b_pe,
                                   pe_scale, pe_bias);
    // BN + softmax + PV
    att_kernel<<<NHB, 256, 0, stream>>>(Ebuf, vtb, pe_scale, pe_bias, obuf);
    // x1 = o @ Wo^T + bo + x   (fp32)
    gemm_nt<1><<<dim3(512, 4), 256, 0, stream>>>(obuf, WOB, CC, CC, bo, x, nullptr, x1);
    // --- BN(x1) ---
    statsA_small<float, 256, 128><<<128, 256, 0, stream>>>(x1, x1part);
    statsB<<<1, 256, 0, stream>>>(x1part, 128, 256, 1.0f / 32768.0f, g0, b0,
                                  bn0_scale, bn0_bias);
    bn_apply_f32<true, 256><<<4096, 256, 0, stream>>>(x1, out1, bn0_scale, bn0_bias);
    gemm_nt<0><<<dim3(512, 8), 256, 0, stream>>>(out1, W0B, 2 * CC, CC, nullptr, nullptr,
                                                 out2, nullptr);
    // --- BN(out2) ---
    statsA_small<bf16, 512, 128><<<128, 256, 0, stream>>>(out2, f1part);
    statsB<<<2, 256, 0, stream>>>(f1part, 128, 512, 1.0f / 32768.0f, g1, b1,
                                  f1_scale, f1_bias);
    bn_apply_bf16<true, 512><<<8192, 256, 0, stream>>>(out2, out4, f1_scale, f1_bias);
    gemm_nt<2><<<dim3(512, 4), 256, 0, stream>>>(out4, W1B, CC, 2 * CC, nullptr, x1,
                                                 nullptr, outp);
    (void)in_sizes; (void)n_in; (void)out_size; (void)ws_size;
}

// Round 10
// 612.095 us; speedup vs baseline: 2.2307x; 1.0179x over previous
//
#include <hip/hip_runtime.h>
#include <hip/hip_bf16.h>

#define HH 8
#define SS 128
#define CC 256
#define DD 32
#define NTOK 32768
#define NHB 2048
#define BNEPS 1e-5f

using bf16 = __hip_bfloat16;
typedef float f32x4 __attribute__((ext_vector_type(4)));
typedef __bf16 bf16x8 __attribute__((ext_vector_type(8)));

__device__ __forceinline__ bf16x8 ld8(const bf16* p) {
    return *reinterpret_cast<const bf16x8*>(p);
}
__device__ __forceinline__ f32x4 ldf4(const float* p) {
    return *reinterpret_cast<const f32x4*>(p);
}
__device__ __forceinline__ void st8(bf16* p, bf16x8 v) {
    *reinterpret_cast<bf16x8*>(p) = v;
}
// bit-pun __bf16 -> __hip_bfloat16 (avoids ambiguous operator=)
__device__ __forceinline__ bf16 bfc(__bf16 x) {
    union { __bf16 i; bf16 o; } u;
    u.i = x;
    return u.o;
}

// ---------------- fp32 -> bf16 weight conversion (all 6 weights, 1 launch) ----------------
__global__ void cvt6(const float* __restrict__ wq, const float* __restrict__ wk,
                     const float* __restrict__ wv, const float* __restrict__ wo,
                     const float* __restrict__ w0, const float* __restrict__ w1,
                     bf16* __restrict__ out) {
    int i = (blockIdx.x * 256 + threadIdx.x) * 4;  // 0..524284
    const float* src;
    int off;
    if (i < 65536) { src = wq; off = i; }
    else if (i < 131072) { src = wk; off = i - 65536; }
    else if (i < 196608) { src = wv; off = i - 131072; }
    else if (i < 262144) { src = wo; off = i - 196608; }
    else if (i < 393216) { src = w0; off = i - 262144; }
    else { src = w1; off = i - 393216; }
    f32x4 v = ldf4(src + off);
#pragma unroll
    for (int u = 0; u < 4; u++) out[i + u] = __float2bfloat16(v[u]);
}

// ---------------- stats stage A (small CH): block-local LDS reduce, NO atomics ----------------
template <typename T, int CH, int P>
__global__ __launch_bounds__(256) void statsA_small(const T* __restrict__ X,
                                                    float* __restrict__ part) {
    constexpr int VEC = (sizeof(T) == 2) ? 8 : 4;
    constexpr int COLV = CH / VEC;
    constexpr int SLOTS = 256 / COLV;
    constexpr int RB = NTOK / P;
    constexpr int ITER = RB / SLOTS;
    int tid = threadIdx.x;
    int cv = tid & (COLV - 1), slot = tid / COLV;
    int c0 = cv * VEC;
    size_t row0 = (size_t)blockIdx.x * RB + slot;
    float s[VEC], s2[VEC];
#pragma unroll
    for (int u = 0; u < VEC; u++) { s[u] = 0.f; s2[u] = 0.f; }
    for (int i = 0; i < ITER; i++) {
        size_t row = row0 + (size_t)i * SLOTS;
        if constexpr (sizeof(T) == 2) {
            bf16x8 v = ld8((const bf16*)X + row * CH + c0);
#pragma unroll
            for (int u = 0; u < VEC; u++) {
                float f = (float)v[u];
                s[u] += f; s2[u] += f * f;
            }
        } else {
            f32x4 v = ldf4((const float*)X + row * CH + c0);
#pragma unroll
            for (int u = 0; u < VEC; u++) {
                float f = v[u];
                s[u] += f; s2[u] += f * f;
            }
        }
    }
    __shared__ float red[256][2 * VEC];
#pragma unroll
    for (int u = 0; u < VEC; u++) {
        red[tid][u] = s[u];
        red[tid][VEC + u] = s2[u];
    }
    __syncthreads();
    if (tid < COLV) {
#pragma unroll
        for (int sl = 1; sl < SLOTS; sl++)
#pragma unroll
            for (int u = 0; u < VEC; u++) {
                s[u] += red[tid + sl * COLV][u];
                s2[u] += red[tid + sl * COLV][VEC + u];
            }
        float* dst = part + (size_t)blockIdx.x * (2 * CH);
#pragma unroll
        for (int u = 0; u < VEC; u++) {
            dst[c0 + u] = s[u];
            dst[CH + c0 + u] = s2[u];
        }
    }
}

// ---------------- stats stage A (wide CH, bf16): disjoint channels, NO atomics ----------------
template <int CH, int P, int ROWS>
__global__ __launch_bounds__(256) void statsA_wide(const bf16* __restrict__ X,
                                                   float* __restrict__ part) {
    constexpr int RB = ROWS / P;
    int c0 = (blockIdx.x * 256 + threadIdx.x) * 8;
    size_t row0 = (size_t)blockIdx.y * RB;
    float s[8], s2[8];
#pragma unroll
    for (int u = 0; u < 8; u++) { s[u] = 0.f; s2[u] = 0.f; }
    for (int i = 0; i < RB; i++) {
        bf16x8 v = ld8(X + (row0 + i) * CH + c0);
#pragma unroll
        for (int u = 0; u < 8; u++) {
            float f = (float)v[u];
            s[u] += f; s2[u] += f * f;
        }
    }
    float* dst = part + (size_t)blockIdx.y * (2 * CH);
#pragma unroll
    for (int u = 0; u < 8; u++) {
        dst[c0 + u] = s[u];
        dst[CH + c0 + u] = s2[u];
    }
}

// ---------------- stage B: reduce partials + finalize -> scale/bias ----------------
__global__ void statsB(const float* __restrict__ part, int P, int nch, float inv_n,
                       const float* __restrict__ gamma, const float* __restrict__ beta,
                       float* __restrict__ scale, float* __restrict__ bias) {
    int c = blockIdx.x * 256 + threadIdx.x;
    if (c >= nch) return;
    float s = 0.f, s2 = 0.f;
    for (int p = 0; p < P; p++) {
        s += part[(size_t)p * 2 * nch + c];
        s2 += part[(size_t)p * 2 * nch + nch + c];
    }
    float mean = s * inv_n;
    float var = s2 * inv_n - mean * mean;
    float rstd = rsqrtf(var + BNEPS);
    float sc = gamma[c] * rstd;
    scale[c] = sc;
    bias[c] = beta[c] - mean * sc;
}

// ---------------- vectorized BN apply (+ReLU) -> bf16 ----------------
template <bool RELU, int CH>
__global__ __launch_bounds__(256) void bn_apply_f32(const float* __restrict__ X,
                                                    bf16* __restrict__ out,
                                                    const float* __restrict__ scale,
                                                    const float* __restrict__ bias) {
    size_t base = ((size_t)blockIdx.x * 256 + threadIdx.x) * 8;
    int c0 = (int)(base & (size_t)(CH - 1));
    f32x4 x0 = ldf4(X + base), x1 = ldf4(X + base + 4);
    f32x4 s0 = ldf4(scale + c0), s1 = ldf4(scale + c0 + 4);
    f32x4 b0 = ldf4(bias + c0), b1 = ldf4(bias + c0 + 4);
    bf16x8 o;
#pragma unroll
    for (int u = 0; u < 4; u++) {
        float v = x0[u] * s0[u] + b0[u];
        if (RELU) v = fmaxf(v, 0.f);
        o[u] = (__bf16)__float2bfloat16(v);
    }
#pragma unroll
    for (int u = 0; u < 4; u++) {
        float v = x1[u] * s1[u] + b1[u];
        if (RELU) v = fmaxf(v, 0.f);
        o[u + 4] = (__bf16)__float2bfloat16(v);
    }
    st8(out + base, o);
}

template <bool RELU, int CH>
__global__ __launch_bounds__(256) void bn_apply_bf16(const bf16* __restrict__ X,
                                                     bf16* __restrict__ out,
                                                     const float* __restrict__ scale,
                                                     const float* __restrict__ bias) {
    size_t base = ((size_t)blockIdx.x * 256 + threadIdx.x) * 8;
    int c0 = (int)(base & (size_t)(CH - 1));
    bf16x8 xv = ld8(X + base);
    f32x4 s0 = ldf4(scale + c0), s1 = ldf4(scale + c0 + 4);
    f32x4 b0 = ldf4(bias + c0), b1 = ldf4(bias + c0 + 4);
    bf16x8 o;
#pragma unroll
    for (int u = 0; u < 4; u++) {
        float v = (float)xv[u] * s0[u] + b0[u];
        if (RELU) v = fmaxf(v, 0.f);
        o[u] = (__bf16)__float2bfloat16(v);
    }
#pragma unroll
    for (int u = 0; u < 4; u++) {
        float v = (float)xv[u + 4] * s1[u] + b1[u];
        if (RELU) v = fmaxf(v, 0.f);
        o[u + 4] = (__bf16)__float2bfloat16(v);
    }
    st8(out + base, o);
}

// ---------------- Fused QKV GEMM: q,k,v all token-major [32768,256] ----------------
__global__ __launch_bounds__(256) void gemm_qkv(
    const bf16* __restrict__ hbuf, const bf16* __restrict__ Wq,
    const bf16* __restrict__ Wk, const bf16* __restrict__ Wv,
    bf16* __restrict__ qb, bf16* __restrict__ kb, bf16* __restrict__ vb) {
    int m0 = blockIdx.x * 64;
    int by = blockIdx.y;            // 0..11
    int mat = by >> 2;              // 0=q 1=k 2=v
    int n0 = (by & 3) * 64;
    const bf16* B = (mat == 0) ? Wq : ((mat == 1) ? Wk : Wv);
    int tid = threadIdx.x;
    int lane = tid & 63, wave = tid >> 6;
    int quad = lane >> 4, l16 = lane & 15;
    int wm = (wave >> 1) * 32, wn = (wave & 1) * 32;
    f32x4 zero = {0.f, 0.f, 0.f, 0.f};
    f32x4 acc[2][2];
#pragma unroll
    for (int i = 0; i < 2; i++)
#pragma unroll
        for (int j = 0; j < 2; j++) acc[i][j] = zero;
    const int K = CC;
#pragma unroll
    for (int kk = 0; kk < K; kk += 32) {
        int kb_ = kk + quad * 8;
        bf16x8 a0 = ld8(hbuf + (size_t)(m0 + wm + l16) * K + kb_);
        bf16x8 a1 = ld8(hbuf + (size_t)(m0 + wm + 16 + l16) * K + kb_);
        bf16x8 b0 = ld8(B + (size_t)(n0 + wn + l16) * K + kb_);
        bf16x8 b1 = ld8(B + (size_t)(n0 + wn + 16 + l16) * K + kb_);
        acc[0][0] = __builtin_amdgcn_mfma_f32_16x16x32_bf16(a0, b0, acc[0][0], 0, 0, 0);
        acc[0][1] = __builtin_amdgcn_mfma_f32_16x16x32_bf16(a0, b1, acc[0][1], 0, 0, 0);
        acc[1][0] = __builtin_amdgcn_mfma_f32_16x16x32_bf16(a1, b0, acc[1][0], 0, 0, 0);
        acc[1][1] = __builtin_amdgcn_mfma_f32_16x16x32_bf16(a1, b1, acc[1][1], 0, 0, 0);
    }
    // LDS transpose epilogue -> 16B coalesced token-major stores
    __shared__ bf16 Ct[64][72];
#pragma unroll
    for (int i = 0; i < 2; i++)
#pragma unroll
        for (int j = 0; j < 2; j++)
#pragma unroll
            for (int r = 0; r < 4; r++)
                Ct[wm + i * 16 + quad * 4 + r][wn + j * 16 + l16] =
                    __float2bfloat16(acc[i][j][r]);
    __syncthreads();
    bf16* dst = (mat == 0) ? qb : ((mat == 1) ? kb : vb);
#pragma unroll
    for (int it = 0; it < 2; it++) {
        int idx = it * 256 + tid;
        int row = idx >> 3, colv = idx & 7;
        bf16x8 c = ld8(&Ct[row][colv * 8]);
        st8(dst + (size_t)(m0 + row) * CC + n0 + colv * 8, c);
    }
}

// ---------------- energy = Q K^T per (n,h): one block per nh, 128x128 tile ----------------
__global__ __launch_bounds__(256) void gemm_energy(const bf16* __restrict__ q,
                                                   const bf16* __restrict__ k,
                                                   bf16* __restrict__ E) {
    int nh = blockIdx.x;
    int nb = nh >> 3, hh = nh & 7;
    int tid = threadIdx.x;
    int lane = tid & 63, wave = tid >> 6;
    int quad = lane >> 4, l16 = lane & 15;
    int wm = (wave >> 1) * 64, wn = (wave & 1) * 64;
    size_t tb = (size_t)nb * SS;
    int cb = hh * DD + quad * 8;
    f32x4 zero = {0.f, 0.f, 0.f, 0.f};
    f32x4 acc[4][4];
#pragma unroll
    for (int i = 0; i < 4; i++)
#pragma unroll
        for (int j = 0; j < 4; j++) acc[i][j] = zero;
    bf16x8 af[4], bfg[4];
#pragma unroll
    for (int i = 0; i < 4; i++)
        af[i] = ld8(q + (tb + wm + i * 16 + l16) * CC + cb);
#pragma unroll
    for (int j = 0; j < 4; j++)
        bfg[j] = ld8(k + (tb + wn + j * 16 + l16) * CC + cb);
#pragma unroll
    for (int i = 0; i < 4; i++)
#pragma unroll
        for (int j = 0; j < 4; j++)
            acc[i][j] = __builtin_amdgcn_mfma_f32_16x16x32_bf16(af[i], bfg[j], acc[i][j], 0, 0, 0);
    __shared__ bf16 Et[128][136];
#pragma unroll
    for (int i = 0; i < 4; i++)
#pragma unroll
        for (int j = 0; j < 4; j++)
#pragma unroll
            for (int r = 0; r < 4; r++)
                Et[wm + i * 16 + quad * 4 + r][wn + j * 16 + l16] =
                    __float2bfloat16(acc[i][j][r]);
    __syncthreads();
    bf16* Eb = E + (size_t)nh * SS * SS;
#pragma unroll
    for (int it = 0; it < 8; it++) {
        int idx = it * 256 + tid;
        int row = idx >> 4, colv = idx & 15;
        st8(Eb + (size_t)row * SS + colv * 8, ld8(&Et[row][colv * 8]));
    }
}

// ---------------- BN(energy) + softmax + P V^T per (n,h) ----------------
__global__ __launch_bounds__(256) void att_kernel(
    const bf16* __restrict__ E, const bf16* __restrict__ v,
    const float* __restrict__ pe_scale, const float* __restrict__ pe_bias,
    bf16* __restrict__ o) {
    __shared__ bf16 P[SS][136];
    __shared__ bf16 Vt[DD][136];
    int nh = blockIdx.x;
    int nb = nh >> 3, hh = nh & 7;
    const bf16* Eb = E + (size_t)nh * SS * SS;
    int tid = threadIdx.x;
    // phase 0: transpose token-major v tile into Vt[d][s]
    {
        int s = tid >> 1, d0 = (tid & 1) * 16;
        const bf16* vp = v + (size_t)(nb * SS + s) * CC + hh * DD + d0;
        bf16x8 v0 = ld8(vp), v1 = ld8(vp + 8);
#pragma unroll
        for (int u = 0; u < 8; u++) {
            Vt[d0 + u][s] = bfc(v0[u]);
            Vt[d0 + 8 + u][s] = bfc(v1[u]);
        }
    }
    // phase 1: affine-BN + 1/sqrt(C) scale -> LDS logits (bf16)
#pragma unroll
    for (int t = 0; t < 8; t++) {
        int e8 = (t * 256 + tid) * 8;
        bf16x8 ev = ld8(Eb + e8);
        f32x4 s0 = ldf4(pe_scale + e8), s1 = ldf4(pe_scale + e8 + 4);
        f32x4 b0 = ldf4(pe_bias + e8), b1 = ldf4(pe_bias + e8 + 4);
        int qi = e8 >> 7, ki = e8 & 127;
        bf16x8 pv;
#pragma unroll
        for (int u = 0; u < 4; u++)
            pv[u] = (__bf16)__float2bfloat16(((float)ev[u] * s0[u] + b0[u]) * 0.0625f);
#pragma unroll
        for (int u = 0; u < 4; u++)
            pv[u + 4] = (__bf16)__float2bfloat16(((float)ev[u + 4] * s1[u] + b1[u]) * 0.0625f);
        st8(&P[qi][ki], pv);
    }
    __syncthreads();
    // phase 2: softmax, one wave owns rows [wave*32, wave*32+32)
    int wave = tid >> 6, lane = tid & 63;
    for (int rr = 0; rr < 32; rr++) {
        int r = wave * 32 + rr;
        float x0 = (float)P[r][lane];
        float x1 = (float)P[r][lane + 64];
        float mx = fmaxf(x0, x1);
#pragma unroll
        for (int off = 32; off; off >>= 1) mx = fmaxf(mx, __shfl_xor(mx, off, 64));
        float e0 = __expf(x0 - mx), e1 = __expf(x1 - mx);
        float sm = e0 + e1;
#pragma unroll
        for (int off = 32; off; off >>= 1) sm += __shfl_xor(sm, off, 64);
        float inv = 1.0f / sm;
        P[r][lane] = __float2bfloat16(e0 * inv);
        P[r][lane + 64] = __float2bfloat16(e1 * inv);
    }
    __syncthreads();
    // phase 3: O = P @ V^T
    int quad = lane >> 4, l16 = lane & 15;
    f32x4 zero = {0.f, 0.f, 0.f, 0.f};
    f32x4 acc[2][2];
#pragma unroll
    for (int i = 0; i < 2; i++)
#pragma unroll
        for (int j = 0; j < 2; j++) acc[i][j] = zero;
#pragma unroll
    for (int kk = 0; kk < SS; kk += 32) {
        int kb_ = kk + quad * 8;
        bf16x8 a0 = ld8(&P[wave * 32 + l16][kb_]);
        bf16x8 a1 = ld8(&P[wave * 32 + 16 + l16][kb_]);
        bf16x8 b0 = ld8(&Vt[l16][kb_]);
        bf16x8 b1 = ld8(&Vt[16 + l16][kb_]);
        acc[0][0] = __builtin_amdgcn_mfma_f32_16x16x32_bf16(a0, b0, acc[0][0], 0, 0, 0);
        acc[0][1] = __builtin_amdgcn_mfma_f32_16x16x32_bf16(a0, b1, acc[0][1], 0, 0, 0);
        acc[1][0] = __builtin_amdgcn_mfma_f32_16x16x32_bf16(a1, b0, acc[1][0], 0, 0, 0);
        acc[1][1] = __builtin_amdgcn_mfma_f32_16x16x32_bf16(a1, b1, acc[1][1], 0, 0, 0);
    }
    __syncthreads();  // all waves done reading P before reuse as O tile
    bf16* Ob = &P[0][0];  // reuse as [128][40]
#pragma unroll
    for (int i = 0; i < 2; i++)
#pragma unroll
        for (int j = 0; j < 2; j++)
#pragma unroll
            for (int r = 0; r < 4; r++) {
                int row = wave * 32 + i * 16 + quad * 4 + r;
                int col = j * 16 + l16;
                Ob[row * 40 + col] = __float2bfloat16(acc[i][j][r]);
            }
    __syncthreads();
#pragma unroll
    for (int it = 0; it < 2; it++) {
        int idx = it * 256 + tid;
        int row = idx >> 2, colv = idx & 3;
        st8(o + (size_t)(nb * SS + row) * CC + hh * DD + colv * 8,
            ld8(&Ob[row * 40 + colv * 8]));
    }
}

// ---------------- Generic NT GEMM with vectorized epilogue ----------------
// MODE 0: out2 = A@B^T, store bf16
// MODE 1: x1 = A@B^T + bias + resf, store fp32
// MODE 2: out = A@B^T + resf, store fp32
template <int MODE>
__global__ __launch_bounds__(256) void gemm_nt(
    const bf16* __restrict__ A, const bf16* __restrict__ B, int N, int K,
    const float* __restrict__ bias, const float* __restrict__ resf,
    bf16* __restrict__ outb, float* __restrict__ outf) {
    int m0 = blockIdx.x * 64, n0 = blockIdx.y * 64;
    int tid = threadIdx.x;
    int lane = tid & 63, wave = tid >> 6;
    int quad = lane >> 4, l16 = lane & 15;
    int wm = (wave >> 1) * 32, wn = (wave & 1) * 32;
    f32x4 zero = {0.f, 0.f, 0.f, 0.f};
    f32x4 acc[2][2];
#pragma unroll
    for (int i = 0; i < 2; i++)
#pragma unroll
        for (int j = 0; j < 2; j++) acc[i][j] = zero;
    for (int kk = 0; kk < K; kk += 32) {
        int kb_ = kk + quad * 8;
        bf16x8 a0 = ld8(A + (size_t)(m0 + wm + l16) * K + kb_);
        bf16x8 a1 = ld8(A + (size_t)(m0 + wm + 16 + l16) * K + kb_);
        bf16x8 b0 = ld8(B + (size_t)(n0 + wn + l16) * K + kb_);
        bf16x8 b1 = ld8(B + (size_t)(n0 + wn + 16 + l16) * K + kb_);
        acc[0][0] = __builtin_amdgcn_mfma_f32_16x16x32_bf16(a0, b0, acc[0][0], 0, 0, 0);
        acc[0][1] = __builtin_amdgcn_mfma_f32_16x16x32_bf16(a0, b1, acc[0][1], 0, 0, 0);
        acc[1][0] = __builtin_amdgcn_mfma_f32_16x16x32_bf16(a1, b0, acc[1][0], 0, 0, 0);
        acc[1][1] = __builtin_amdgcn_mfma_f32_16x16x32_bf16(a1, b1, acc[1][1], 0, 0, 0);
    }
    __shared__ float Cf[64][72];
#pragma unroll
    for (int i = 0; i < 2; i++)
#pragma unroll
        for (int j = 0; j < 2; j++)
#pragma unroll
            for (int r = 0; r < 4; r++)
                Cf[wm + i * 16 + quad * 4 + r][wn + j * 16 + l16] = acc[i][j][r];
    __syncthreads();
#pragma unroll
    for (int it = 0; it < 2; it++) {
        int idx = it * 256 + tid;
        int row = idx >> 3, colv = idx & 7;
        f32x4 v0 = ldf4(&Cf[row][colv * 8]);
        f32x4 v1 = ldf4(&Cf[row][colv * 8 + 4]);
        int gcol = n0 + colv * 8;
        size_t gi = (size_t)(m0 + row) * N + gcol;
        if (MODE == 0) {
            bf16x8 ob;
#pragma unroll
            for (int u = 0; u < 4; u++) {
                ob[u] = (__bf16)__float2bfloat16(v0[u]);
                ob[u + 4] = (__bf16)__float2bfloat16(v1[u]);
            }
            st8(outb + gi, ob);
        } else if (MODE == 1) {
            f32x4 bb0 = ldf4(bias + gcol), bb1 = ldf4(bias + gcol + 4);
            f32x4 r0 = ldf4(resf + gi), r1 = ldf4(resf + gi + 4);
            v0 = v0 + bb0 + r0;
            v1 = v1 + bb1 + r1;
            *reinterpret_cast<f32x4*>(outf + gi) = v0;
            *reinterpret_cast<f32x4*>(outf + gi + 4) = v1;
        } else {
            f32x4 r0 = ldf4(resf + gi), r1 = ldf4(resf + gi + 4);
            v0 = v0 + r0;
            v1 = v1 + r1;
            *reinterpret_cast<f32x4*>(outf + gi) = v0;
            *reinterpret_cast<f32x4*>(outf + gi + 4) = v1;
        }
    }
}

// ---------------- workspace layout (bytes) ----------------
#define WB_OFF 0u
#define HB_OFF 1048576u
#define Q_OFF 17825792u
#define K_OFF 34603008u
#define VT_OFF 51380224u
#define E_OFF 68157440u
#define O_OFF 1048576u      /* reuse hbuf */
#define X1_OFF 17825792u    /* fp32, over q+k */
#define OUT1_OFF 51380224u  /* over v */
#define OUT2_OFF 68157440u  /* over E 1st half */
#define OUT4_OFF 101711872u /* over E 2nd half */
/* transient scale/bias + partial homes (dead windows):
   bn1 s/b  -> E_OFF (2 KB);      x  partial -> E_OFF+64K (256 KB)   [E dead until energy]
   pe  s/b  -> Q_OFF (128 KB);    pe partial -> Q_OFF+128K (4 MB)    [q dead after energy]
   bn0 s/b  -> HB_OFF (2 KB);     x1 partial -> HB_OFF+16K (256 KB)  [obuf dead after Wo gemm]
   f1  s/b  -> HB_OFF+4K (4 KB);  f1 partial -> HB_OFF+16K (512 KB) */

extern "C" void kernel_launch(void* const* d_in, const int* in_sizes, int n_in,
                              void* d_out, int out_size, void* d_ws, size_t ws_size,
                              hipStream_t stream) {
    const float* x = (const float*)d_in[0];
    const float* g_n = (const float*)d_in[1];
    const float* b_n = (const float*)d_in[2];
    const float* Wq = (const float*)d_in[3];
    const float* Wk = (const float*)d_in[4];
    const float* Wv = (const float*)d_in[5];
    const float* Wo = (const float*)d_in[6];
    const float* bo = (const float*)d_in[7];
    const float* g_pe = (const float*)d_in[8];
    const float* b_pe = (const float*)d_in[9];
    const float* g0 = (const float*)d_in[10];
    const float* b0 = (const float*)d_in[11];
    const float* W0 = (const float*)d_in[12];
    const float* g1 = (const float*)d_in[13];
    const float* b1 = (const float*)d_in[14];
    const float* W1 = (const float*)d_in[15];

    char* ws = (char*)d_ws;
    bf16* WB = (bf16*)(ws + WB_OFF);
    bf16* WQB = WB;
    bf16* WKB = WB + 65536;
    bf16* WVB = WB + 131072;
    bf16* WOB = WB + 196608;
    bf16* W0B = WB + 262144;
    bf16* W1B = WB + 393216;
    bf16* hbuf = (bf16*)(ws + HB_OFF);
    bf16* qb = (bf16*)(ws + Q_OFF);
    bf16* kb = (bf16*)(ws + K_OFF);
    bf16* vb = (bf16*)(ws + VT_OFF);
    bf16* Ebuf = (bf16*)(ws + E_OFF);
    bf16* obuf = (bf16*)(ws + O_OFF);
    float* x1 = (float*)(ws + X1_OFF);
    bf16* out1 = (bf16*)(ws + OUT1_OFF);
    bf16* out2 = (bf16*)(ws + OUT2_OFF);
    bf16* out4 = (bf16*)(ws + OUT4_OFF);
    float* bn1_scale = (float*)(ws + E_OFF);
    float* bn1_bias = bn1_scale + 256;
    float* xpart = (float*)(ws + E_OFF + 65536);
    float* pe_scale = (float*)(ws + Q_OFF);
    float* pe_bias = pe_scale + 16384;
    float* pepart = (float*)(ws + Q_OFF + 131072);
    float* bn0_scale = (float*)(ws + HB_OFF);
    float* bn0_bias = bn0_scale + 256;
    float* f1_scale = (float*)(ws + HB_OFF + 4096);
    float* f1_bias = f1_scale + 512;
    float* x1part = (float*)(ws + HB_OFF + 16384);
    float* f1part = (float*)(ws + HB_OFF + 16384);
    float* outp = (float*)d_out;

    // weights fp32 -> bf16
    cvt6<<<512, 256, 0, stream>>>(Wq, Wk, Wv, Wo, W0, W1, WB);
    // --- BN(x) ---
    statsA_small<float, 256, 128><<<128, 256, 0, stream>>>(x, xpart);
    statsB<<<1, 256, 0, stream>>>(xpart, 128, 256, 1.0f / 32768.0f, g_n, b_n,
                                  bn1_scale, bn1_bias);
    bn_apply_f32<false, 256><<<4096, 256, 0, stream>>>(x, hbuf, bn1_scale, bn1_bias);
    // QKV (token-major outputs)
    gemm_qkv<<<dim3(512, 12), 256, 0, stream>>>(hbuf, WQB, WKB, WVB, qb, kb, vb);
    // energy: one block per (n,h)
    gemm_energy<<<NHB, 256, 0, stream>>>(qb, kb, Ebuf);
    // --- BN(energy) ---
    statsA_wide<16384, 32, 2048><<<dim3(8, 32), 256, 0, stream>>>(Ebuf, pepart);
    statsB<<<64, 256, 0, stream>>>(pepart, 32, 16384, 1.0f / 2048.0f, g_pe, b_pe,
                                   pe_scale, pe_bias);
    // BN + softmax + PV
    att_kernel<<<NHB, 256, 0, stream>>>(Ebuf, vb, pe_scale, pe_bias, obuf);
    // x1 = o @ Wo^T + bo + x   (fp32)
    gemm_nt<1><<<dim3(512, 4), 256, 0, stream>>>(obuf, WOB, CC, CC, bo, x, nullptr, x1);
    // --- BN(x1) ---
    statsA_small<float, 256, 128><<<128, 256, 0, stream>>>(x1, x1part);
    statsB<<<1, 256, 0, stream>>>(x1part, 128, 256, 1.0f / 32768.0f, g0, b0,
                                  bn0_scale, bn0_bias);
    bn_apply_f32<true, 256><<<4096, 256, 0, stream>>>(x1, out1, bn0_scale, bn0_bias);
    gemm_nt<0><<<dim3(512, 8), 256, 0, stream>>>(out1, W0B, 2 * CC, CC, nullptr, nullptr,
                                                 out2, nullptr);
    // --- BN(out2) ---
    statsA_small<bf16, 512, 128><<<128, 256, 0, stream>>>(out2, f1part);
    statsB<<<2, 256, 0, stream>>>(f1part, 128, 512, 1.0f / 32768.0f, g1, b1,
                                  f1_scale, f1_bias);
    bn_apply_bf16<true, 512><<<8192, 256, 0, stream>>>(out2, out4, f1_scale, f1_bias);
    gemm_nt<2><<<dim3(512, 4), 256, 0, stream>>>(out4, W1B, CC, 2 * CC, nullptr, x1,
                                                 nullptr, outp);
    (void)in_sizes; (void)n_in; (void)out_size; (void)ws_size;
}